// Round 4
// baseline (335.037 us; speedup 1.0000x reference)
//
#include <hip/hip_runtime.h>
#include <math.h>

// Problem: B=16, C=128, H=W=64 -> N = 8,388,608 f32 elements.
// Reference collapses analytically:
//   softmax(w).sum(axis=1) == 1   =>  integral(d, param, idx) == param[idx]
//   linspace tables are affine    =>  interplot == a + b*index
//   theta = -pi + 2*pi*sigmoid(d) =>  sin(theta) = -sin(2*pi*sg), cos likewise
//   ds    = e * |tanh(d)|
//   pre   = d*exp(ds*sin th) + ds*cos th
// Global mean/std (ddof=1) normalize of input (x iscale) and of pre (x oscale).
//
// Round-3 lesson: cg::grid.sync() is a non-inlined call -> compiler spilled the
// 32 per-thread data registers to scratch (VGPR_Count=32!), 182us. This round:
// same fused single-kernel shape, but (a) NO state carried across syncs -- the
// input is re-read each phase (L3-resident after phase A), and (b) a hand-rolled
// inline grid barrier with scoped atomics instead of cooperative groups.
// Co-residency: __launch_bounds__(256,4) => <=128 VGPR => 4 blocks/CU x 256 CU
// = 1024 blocks, exactly the grid we launch, so the spin barrier cannot hang.

#define NTOT 8388608
#define NV   (NTOT / 4)          // 2,097,152 float4
#define GA   1024                // blocks
#define TB   256                 // threads per block
#define STRIDE (GA * TB)         // 262,144 threads
#define ITERS  (NV / STRIDE)     // 8 float4 per thread per pass

__device__ __forceinline__ float fast_rcp(float x) {
    return __builtin_amdgcn_rcpf(x);
}

// x -> pre-normalization output value. m1 = mean(data), k1 = iscale/std(data).
__device__ __forceinline__ float lnon_elem(float x, float m1, float k1) {
    float d  = (x - m1) * k1;
    float a  = fminf(fabsf(d), 30.0f);       // saturation guard
    float Ea = __expf(a);                    // e^{|d|}, shared by sigmoid & tanh
    float sg = (d >= 0.0f ? Ea : 1.0f) * fast_rcp(1.0f + Ea);   // sigmoid(d)
    float t  = 1.0f - 2.0f * fast_rcp(1.0f + Ea * Ea);          // tanh(|d|)
    float dsv = 2.71828182845904523f * t;                       // ds
    // theta = 2*pi*sg - pi; v_sin/cos_f32 take REVOLUTIONS: sin(2*pi*sg).
    float sn = -__builtin_amdgcn_sinf(sg);
    float cs = -__builtin_amdgcn_cosf(sg);
    return fmaf(d, __expf(dsv * sn), dsv * cs);
}

// Reduce a double pair across the 256-thread block; result valid in ALL threads.
__device__ __forceinline__ void block_reduce2(double& s, double& q) {
    #pragma unroll
    for (int off = 32; off > 0; off >>= 1) {
        s += __shfl_down(s, off);
        q += __shfl_down(q, off);
    }
    __shared__ double lds[4][2];
    const int wave = threadIdx.x >> 6;
    const int lane = threadIdx.x & 63;
    __syncthreads();                          // guard LDS reuse across calls
    if (lane == 0) { lds[wave][0] = s; lds[wave][1] = q; }
    __syncthreads();
    s = lds[0][0] + lds[1][0] + lds[2][0] + lds[3][0];
    q = lds[0][1] + lds[1][1] + lds[2][1] + lds[3][1];
}

__device__ __forceinline__ void stats_from(double s, double q, float sc,
                                           float& m, float& k) {
    const double Nd = (double)NTOT;
    double mean = s / Nd;
    double var  = (q - s * s / Nd) / (Nd - 1.0);
    m = (float)mean;
    k = (float)(1.0 / sqrt(var)) * sc;
}

// One-shot grid barrier on counter slot `slot` (zeroed by k_init each launch).
// Arrive: release via fetch_add(AGENT). Wait: thread 0 spins; then the whole
// block takes an agent-scope acquire fence so subsequent plain loads see all
// pre-barrier writes from every block.
__device__ __forceinline__ void grid_barrier(unsigned* bar, int slot) {
    __syncthreads();
    if (threadIdx.x == 0) {
        __hip_atomic_fetch_add(&bar[slot * 32], 1u,
                               __ATOMIC_ACQ_REL, __HIP_MEMORY_SCOPE_AGENT);
        while (__hip_atomic_load(&bar[slot * 32],
                                 __ATOMIC_ACQUIRE, __HIP_MEMORY_SCOPE_AGENT)
               < (unsigned)GA) {
            __builtin_amdgcn_s_sleep(2);
        }
    }
    __syncthreads();
    __builtin_amdgcn_fence(__ATOMIC_ACQUIRE, "agent");
}

__global__ void k_init(unsigned* bar) {
    if (threadIdx.x < 64) bar[threadIdx.x] = 0u;   // both slots (stride-32 dwords)
}

__global__ __launch_bounds__(TB, 4) void k_fused(
        const float4* __restrict__ in,
        const float*  __restrict__ iscale,
        const float*  __restrict__ oscale,
        double2*      __restrict__ P1,
        double2*      __restrict__ P2,
        unsigned*     __restrict__ bar,
        float4*       __restrict__ out) {
    const int t = blockIdx.x * TB + threadIdx.x;

    // ---- Phase A: input sum/sumsq (32 MB HBM read, populates L3) ----
    {
        float s = 0.0f, q = 0.0f;
        #pragma unroll
        for (int k = 0; k < ITERS; ++k) {
            float4 v = in[t + k * STRIDE];
            s += v.x + v.y + v.z + v.w;
            q += v.x * v.x + v.y * v.y + v.z * v.z + v.w * v.w;
        }
        double s1 = (double)s, q1 = (double)q;
        block_reduce2(s1, q1);
        if (threadIdx.x == 0) P1[blockIdx.x] = make_double2(s1, q1);
    }
    grid_barrier(bar, 0);

    // ---- Phase B: reduce P1 -> (m1,k1); re-read input (L3), pre-out stats ----
    float m1, k1;
    {
        double s1 = 0.0, q1 = 0.0;
        #pragma unroll
        for (int i = threadIdx.x; i < GA; i += TB) {
            s1 += __hip_atomic_load(&P1[i].x, __ATOMIC_RELAXED,
                                    __HIP_MEMORY_SCOPE_AGENT);
            q1 += __hip_atomic_load(&P1[i].y, __ATOMIC_RELAXED,
                                    __HIP_MEMORY_SCOPE_AGENT);
        }
        block_reduce2(s1, q1);
        stats_from(s1, q1, iscale[0], m1, k1);

        float s = 0.0f, q = 0.0f;
        #pragma unroll
        for (int k = 0; k < ITERS; ++k) {
            float4 v = in[t + k * STRIDE];
            float p0 = lnon_elem(v.x, m1, k1);
            float p1 = lnon_elem(v.y, m1, k1);
            float p2 = lnon_elem(v.z, m1, k1);
            float p3 = lnon_elem(v.w, m1, k1);
            s += p0 + p1 + p2 + p3;
            q += p0 * p0 + p1 * p1 + p2 * p2 + p3 * p3;
        }
        double s2 = (double)s, q2 = (double)q;
        block_reduce2(s2, q2);
        if (threadIdx.x == 0) P2[blockIdx.x] = make_double2(s2, q2);
    }
    grid_barrier(bar, 1);

    // ---- Phase C: reduce P2 -> (m2,k2); re-read, recompute, store ----
    {
        double s2 = 0.0, q2 = 0.0;
        #pragma unroll
        for (int i = threadIdx.x; i < GA; i += TB) {
            s2 += __hip_atomic_load(&P2[i].x, __ATOMIC_RELAXED,
                                    __HIP_MEMORY_SCOPE_AGENT);
            q2 += __hip_atomic_load(&P2[i].y, __ATOMIC_RELAXED,
                                    __HIP_MEMORY_SCOPE_AGENT);
        }
        block_reduce2(s2, q2);
        float m2, k2;
        stats_from(s2, q2, oscale[0], m2, k2);

        #pragma unroll
        for (int k = 0; k < ITERS; ++k) {
            float4 v = in[t + k * STRIDE];
            float4 o;
            o.x = (lnon_elem(v.x, m1, k1) - m2) * k2;
            o.y = (lnon_elem(v.y, m1, k1) - m2) * k2;
            o.z = (lnon_elem(v.z, m1, k1) - m2) * k2;
            o.w = (lnon_elem(v.w, m1, k1) - m2) * k2;
            out[t + k * STRIDE] = o;
        }
    }
}

extern "C" void kernel_launch(void* const* d_in, const int* in_sizes, int n_in,
                              void* d_out, int out_size, void* d_ws, size_t ws_size,
                              hipStream_t stream) {
    const float4* data   = (const float4*)d_in[0];
    const float*  iscale = (const float*)d_in[1];
    const float*  oscale = (const float*)d_in[2];
    // d_in[3..6] (weight_sp, weight_ch, conv_w, conv_b): mathematically dead
    // (softmax row-sums are identically 1).
    float4*   out = (float4*)d_out;
    double2*  P1  = (double2*)d_ws;            // GA entries
    double2*  P2  = P1 + GA;                   // GA entries
    unsigned* bar = (unsigned*)(P2 + GA);      // 2 slots, 128B apart

    hipLaunchKernelGGL(k_init, dim3(1), dim3(64), 0, stream, bar);
    hipLaunchKernelGGL(k_fused, dim3(GA), dim3(TB), 0, stream,
                       data, iscale, oscale, P1, P2, bar, out);
}

// Round 6
// 116.148 us; speedup vs baseline: 2.8846x; 2.8846x over previous
//
#include <hip/hip_runtime.h>
#include <math.h>

// Problem: B=16, C=128, H=W=64 -> N = 8,388,608 f32 elements.
// Reference collapses analytically:
//   softmax(w).sum(axis=1) == 1   =>  integral(d, param, idx) == param[idx]
//   linspace tables are affine    =>  interplot == a + b*index
//   theta = -pi + 2*pi*sigmoid(d) =>  sin(theta) = -sin(2*pi*sg), cos likewise
//   ds    = e * |tanh(d)|
//   pre   = d*exp(ds*sin th) + ds*cos th
// Global mean/std (ddof=1) normalize of input (x iscale) and of pre (x oscale).
//
// Round-3/4 lesson (measured twice): in-kernel grid-wide barriers are ~100us
// each on MI355X (cg spills registers; hand-rolled scoped-atomic spin
// serializes at the cross-XCD coherence point). Kernel boundaries are the
// cheap grid barrier. Also: dur_us carries ~60-90us of harness work (256MiB
// d_ws poison fill = 42us, d_in restore, d_out poison) that we cannot remove.
//
// Structure: 3 kernels, no atomics, per-block partials + redundant reduce.
//   k_s1: input sum/sumsq -> P1
//   k_s2: P1 -> (m1,k1); y = lnon_elem(x); write y to d_out; y-stats -> P2
//   k_s3: P2 -> (m2,k2); d_out = (d_out - m2)*k2   (pure affine, L3-hot)
// Transcendentals run ONCE (round 2 ran them twice).
//
// (Round 5 was an infra failure -- "container failed twice" -- this is the
// same kernel resubmitted.)

#define NTOT 8388608
#define NV   (NTOT / 4)          // 2,097,152 float4
#define GA   2048                // blocks = 8 blocks/CU x 256 CU
#define TB   256                 // threads per block
#define STRIDE (GA * TB)         // 524,288 threads
#define ITERS  (NV / STRIDE)     // 4 float4 per thread, fully unrolled

__device__ __forceinline__ float fast_rcp(float x) {
    return __builtin_amdgcn_rcpf(x);
}

// x -> pre-normalization output value. m1 = mean(data), k1 = iscale/std(data).
__device__ __forceinline__ float lnon_elem(float x, float m1, float k1) {
    float d  = (x - m1) * k1;
    float a  = fminf(fabsf(d), 30.0f);       // saturation guard
    float Ea = __expf(a);                    // e^{|d|}, shared by sigmoid & tanh
    float sg = (d >= 0.0f ? Ea : 1.0f) * fast_rcp(1.0f + Ea);   // sigmoid(d)
    float t  = 1.0f - 2.0f * fast_rcp(1.0f + Ea * Ea);          // tanh(|d|)
    float dsv = 2.71828182845904523f * t;                       // ds
    // theta = 2*pi*sg - pi; v_sin/cos_f32 take REVOLUTIONS: sin(2*pi*sg).
    float sn = -__builtin_amdgcn_sinf(sg);
    float cs = -__builtin_amdgcn_cosf(sg);
    return fmaf(d, __expf(dsv * sn), dsv * cs);
}

// Reduce a double pair across the 256-thread block; result valid in ALL threads.
__device__ __forceinline__ void block_reduce2(double& s, double& q) {
    #pragma unroll
    for (int off = 32; off > 0; off >>= 1) {
        s += __shfl_down(s, off);
        q += __shfl_down(q, off);
    }
    __shared__ double lds[4][2];
    const int wave = threadIdx.x >> 6;
    const int lane = threadIdx.x & 63;
    __syncthreads();
    if (lane == 0) { lds[wave][0] = s; lds[wave][1] = q; }
    __syncthreads();
    s = lds[0][0] + lds[1][0] + lds[2][0] + lds[3][0];
    q = lds[0][1] + lds[1][1] + lds[2][1] + lds[3][1];
}

__device__ __forceinline__ void stats_from(double s, double q, float sc,
                                           float& m, float& k) {
    const double Nd = (double)NTOT;
    double mean = s / Nd;
    double var  = (q - s * s / Nd) / (Nd - 1.0);
    m = (float)mean;
    k = (float)(1.0 / sqrt(var)) * sc;
}

// Pass 1: per-block {sum, sumsq} of raw data -> P1[blockIdx].
__global__ __launch_bounds__(TB, 8) void k_s1(const float4* __restrict__ in,
                                              double2* __restrict__ P1) {
    const int t = blockIdx.x * TB + threadIdx.x;
    float s = 0.0f, q = 0.0f;
    #pragma unroll
    for (int k = 0; k < ITERS; ++k) {
        float4 v = in[t + k * STRIDE];
        s += v.x + v.y + v.z + v.w;
        q += v.x * v.x + v.y * v.y + v.z * v.z + v.w * v.w;
    }
    double s1 = (double)s, q1 = (double)q;
    block_reduce2(s1, q1);
    if (threadIdx.x == 0) P1[blockIdx.x] = make_double2(s1, q1);
}

// Pass 2: reduce P1 -> (m1,k1); y = lnon_elem(x) -> out; y-stats -> P2.
__global__ __launch_bounds__(TB, 8) void k_s2(const float4* __restrict__ in,
                                              const float* __restrict__ iscale,
                                              const double2* __restrict__ P1,
                                              double2* __restrict__ P2,
                                              float4* __restrict__ out) {
    double s1 = 0.0, q1 = 0.0;
    #pragma unroll
    for (int i = threadIdx.x; i < GA; i += TB) {
        double2 p = P1[i];
        s1 += p.x; q1 += p.y;
    }
    block_reduce2(s1, q1);
    float m1, k1;
    stats_from(s1, q1, iscale[0], m1, k1);

    const int t = blockIdx.x * TB + threadIdx.x;
    float s = 0.0f, q = 0.0f;
    #pragma unroll
    for (int k = 0; k < ITERS; ++k) {
        float4 v = in[t + k * STRIDE];
        float4 y;
        y.x = lnon_elem(v.x, m1, k1);
        y.y = lnon_elem(v.y, m1, k1);
        y.z = lnon_elem(v.z, m1, k1);
        y.w = lnon_elem(v.w, m1, k1);
        out[t + k * STRIDE] = y;
        s += y.x + y.y + y.z + y.w;
        q += y.x * y.x + y.y * y.y + y.z * y.z + y.w * y.w;
    }
    double s2 = (double)s, q2 = (double)q;
    block_reduce2(s2, q2);
    if (threadIdx.x == 0) P2[blockIdx.x] = make_double2(s2, q2);
}

// Pass 3: reduce P2 -> (m2,k2); in-place affine rescale of out (L3-hot).
__global__ __launch_bounds__(TB, 8) void k_s3(const float* __restrict__ oscale,
                                              const double2* __restrict__ P2,
                                              float4* __restrict__ out) {
    double s2 = 0.0, q2 = 0.0;
    #pragma unroll
    for (int i = threadIdx.x; i < GA; i += TB) {
        double2 p = P2[i];
        s2 += p.x; q2 += p.y;
    }
    block_reduce2(s2, q2);
    float m2, k2;
    stats_from(s2, q2, oscale[0], m2, k2);

    const int t = blockIdx.x * TB + threadIdx.x;
    #pragma unroll
    for (int k = 0; k < ITERS; ++k) {
        float4 y = out[t + k * STRIDE];
        y.x = (y.x - m2) * k2;
        y.y = (y.y - m2) * k2;
        y.z = (y.z - m2) * k2;
        y.w = (y.w - m2) * k2;
        out[t + k * STRIDE] = y;
    }
}

extern "C" void kernel_launch(void* const* d_in, const int* in_sizes, int n_in,
                              void* d_out, int out_size, void* d_ws, size_t ws_size,
                              hipStream_t stream) {
    const float4* data   = (const float4*)d_in[0];
    const float*  iscale = (const float*)d_in[1];
    const float*  oscale = (const float*)d_in[2];
    // d_in[3..6] (weight_sp, weight_ch, conv_w, conv_b): mathematically dead
    // (softmax row-sums are identically 1).
    float4*  out = (float4*)d_out;
    double2* P1  = (double2*)d_ws;        // GA entries
    double2* P2  = P1 + GA;               // GA entries (64 KiB total)

    hipLaunchKernelGGL(k_s1, dim3(GA), dim3(TB), 0, stream, data, P1);
    hipLaunchKernelGGL(k_s2, dim3(GA), dim3(TB), 0, stream, data, iscale, P1, P2, out);
    hipLaunchKernelGGL(k_s3, dim3(GA), dim3(TB), 0, stream, oscale, P2, out);
}